// Round 2
// baseline (10708.172 us; speedup 1.0000x reference)
//
#include <hip/hip_runtime.h>
#include <math.h>

#define BB 512
#define SS 64
#define TT 32
#define VV 128
#define EE 256
#define HH 512
#define DENC 1024
#define BH (BB*HH)
#define XW0 1792   // E + DENC + H
#define XW1 1024   // H + H
#define PW  1792   // H + DENC + E
#define G4H 2048   // 4*H

__device__ __forceinline__ float sigf(float x){ return 1.f/(1.f+expf(-x)); }

// C = A @ Bt.T (+bias1+bias2) ; A:(M,K) row-major, Bt:(N,K) row-major.
// ATOMIC=true: atomicAdd into C (C must be pre-initialized), used with split-K (gridDim.z).
template<int BM,int BN,int BK,bool ATOMIC>
__global__ __launch_bounds__(256)
void gemm_tn(float* __restrict__ C, const float* __restrict__ A, const float* __restrict__ Bt,
             const float* __restrict__ bias1, const float* __restrict__ bias2,
             int M, int N, int K, int kChunk, int ldc, int cOff)
{
  constexpr int LDA = BM+4, LDB = BN+4;
  __shared__ __align__(16) float As[BK*LDA];
  __shared__ __align__(16) float Bs[BK*LDB];
  const int tid = threadIdx.x;
  const int tx = tid & 15, ty = tid >> 4;
  const int rowBase = blockIdx.y*BM, colBase = blockIdx.x*BN;
  const int k0 = blockIdx.z*kChunk, k1 = k0 + kChunk;
  float acc[4][4] = {};
  for (int kt = k0; kt < k1; kt += BK) {
    #pragma unroll
    for (int i = 0; i < (BM*BK)/256; ++i) {
      int t2 = tid + i*256;
      int m = t2 / BK, k = t2 % BK;
      As[k*LDA + m] = A[(size_t)(rowBase+m)*K + kt + k];
    }
    #pragma unroll
    for (int i = 0; i < (BN*BK)/256; ++i) {
      int t2 = tid + i*256;
      int n = t2 / BK, k = t2 % BK;
      Bs[k*LDB + n] = Bt[(size_t)(colBase+n)*K + kt + k];
    }
    __syncthreads();
    #pragma unroll
    for (int k = 0; k < BK; ++k) {
      float a4[4], b4[4];
      *(float4*)a4 = *(const float4*)&As[k*LDA + ty*4];
      *(float4*)b4 = *(const float4*)&Bs[k*LDB + tx*4];
      #pragma unroll
      for (int i = 0; i < 4; ++i)
        #pragma unroll
        for (int j = 0; j < 4; ++j)
          acc[i][j] += a4[i]*b4[j];
    }
    __syncthreads();
  }
  const int r = rowBase + ty*4, cc = colBase + tx*4;
  if (ATOMIC) {
    #pragma unroll
    for (int i = 0; i < 4; ++i)
      #pragma unroll
      for (int j = 0; j < 4; ++j)
        atomicAdd(&C[(size_t)(r+i)*ldc + cOff + cc + j], acc[i][j]);
  } else {
    float bv[4] = {0.f,0.f,0.f,0.f};
    if (bias1) {
      #pragma unroll
      for (int j = 0; j < 4; ++j) bv[j] += bias1[cc+j];
    }
    if (bias2) {
      #pragma unroll
      for (int j = 0; j < 4; ++j) bv[j] += bias2[cc+j];
    }
    #pragma unroll
    for (int i = 0; i < 4; ++i)
      #pragma unroll
      for (int j = 0; j < 4; ++j)
        C[(size_t)(r+i)*ldc + cOff + cc + j] = acc[i][j] + bv[j];
  }
}

// One block per batch element b: attention scores + masked softmax + context,
// plus assembling xcat0 = [emb_t | context | h0_prev] and predcat[ctx, emb] parts.
__global__ __launch_bounds__(256)
void attn_kernel(const float* __restrict__ dec_proj, const float* __restrict__ enc_proj,
                 const float* __restrict__ enc_out, const float* __restrict__ vvec,
                 const int* __restrict__ mask, const int* __restrict__ targets,
                 const float* __restrict__ emb, const float* __restrict__ h,
                 float* __restrict__ xcat0, float* __restrict__ predcat, int t)
{
  const int b = blockIdx.x;
  const int tid = threadIdx.x;
  const int lane = tid & 63, wave = tid >> 6;
  __shared__ float sc[SS];
  __shared__ float wt[SS];

  // preload this lane's h-slice of dec_proj and v
  float dp[8], vr[8];
  #pragma unroll
  for (int i = 0; i < 8; ++i) {
    int hh = lane + 64*i;
    dp[i] = dec_proj[b*HH + hh];
    vr[i] = vvec[hh];
  }
  const float* epb = enc_proj + (size_t)b*SS*HH;
  // each wave handles 16 s values
  for (int s = wave*16; s < wave*16 + 16; ++s) {
    float acc = 0.f;
    #pragma unroll
    for (int i = 0; i < 8; ++i) {
      float e = tanhf(dp[i] + epb[s*HH + lane + 64*i]);
      acc += e * vr[i];
    }
    #pragma unroll
    for (int off = 32; off; off >>= 1) acc += __shfl_down(acc, off, 64);
    if (lane == 0) sc[s] = acc;
  }
  __syncthreads();
  // masked softmax over S=64 (wave 0)
  if (wave == 0) {
    int valid = mask[b*SS + lane];
    float x = valid ? sc[lane] : -INFINITY;
    float mx = x;
    #pragma unroll
    for (int off = 32; off; off >>= 1) mx = fmaxf(mx, __shfl_xor(mx, off, 64));
    float e = valid ? expf(x - mx) : 0.f;
    float sum = e;
    #pragma unroll
    for (int off = 32; off; off >>= 1) sum += __shfl_xor(sum, off, 64);
    wt[lane] = e / sum;
  }
  __syncthreads();
  // context = sum_s wt[s] * enc_out[b,s,:]
  const float* eob = enc_out + (size_t)b*SS*DENC;
  for (int d = tid; d < DENC; d += 256) {
    float acc = 0.f;
    #pragma unroll
    for (int s = 0; s < SS; ++s) acc += wt[s]*eob[s*DENC + d];
    xcat0[(size_t)b*XW0 + EE + d] = acc;
    predcat[(size_t)b*PW + HH + d] = acc;
  }
  // embedded token (teacher forcing: t==0 -> EOS=2, else targets[b,t-1])
  int tok = (t == 0) ? 2 : targets[b*TT + t - 1];
  float ev = emb[tok*EE + tid];           // tid < 256 == E
  xcat0[(size_t)b*XW0 + tid] = ev;
  predcat[(size_t)b*PW + HH + DENC + tid] = ev;
  // h0_prev into xcat0 tail
  for (int j = tid; j < HH; j += 256)
    xcat0[(size_t)b*XW0 + EE + DENC + j] = h[b*HH + j];
}

__global__ __launch_bounds__(256)
void lstm_ew0(const float* __restrict__ gates, float* __restrict__ h, float* __restrict__ c,
              float* __restrict__ xcat1)
{
  int idx = blockIdx.x*256 + threadIdx.x;       // 0..BH-1
  int b = idx >> 9, hh = idx & 511;
  const float* g = gates + (size_t)b*G4H;
  float gi = g[hh], gf = g[HH+hh], gg = g[2*HH+hh], go = g[3*HH+hh];
  float cp = c[idx];
  float cn = sigf(gf)*cp + sigf(gi)*tanhf(gg);
  float hn = sigf(go)*tanhf(cn);
  c[idx] = cn; h[idx] = hn;
  xcat1[(size_t)b*XW1 + hh] = hn;               // h0_new
  xcat1[(size_t)b*XW1 + HH + hh] = h[BH + idx]; // h1_prev (not yet updated)
}

__global__ __launch_bounds__(256)
void lstm_ew1(const float* __restrict__ gates, float* __restrict__ h, float* __restrict__ c,
              float* __restrict__ predcat, float* __restrict__ dec_proj,
              float* __restrict__ out, const float* __restrict__ b_out, int t)
{
  int idx = blockIdx.x*256 + threadIdx.x;       // 0..BH-1
  int b = idx >> 9, hh = idx & 511;
  const float* g = gates + (size_t)b*G4H;
  float gi = g[hh], gf = g[HH+hh], gg = g[2*HH+hh], go = g[3*HH+hh];
  float cp = c[BH + idx];
  float cn = sigf(gf)*cp + sigf(gi)*tanhf(gg);
  float hn = sigf(go)*tanhf(cn);
  c[BH + idx] = cn; h[BH + idx] = hn;
  predcat[(size_t)b*PW + hh] = hn;
  dec_proj[idx] = 0.f;                          // zero for next step's split-K GEMM
  if (idx < BB*VV) {                            // init out[:, t, :] = b_out
    int b2 = idx >> 7, v2 = idx & 127;
    out[(size_t)(b2*TT + t)*VV + v2] = b_out[v2];
  }
}

__global__ __launch_bounds__(256)
void build_wcat(float* __restrict__ wcat0, float* __restrict__ wcat1,
                const float* __restrict__ wih0, const float* __restrict__ whh0,
                const float* __restrict__ wih1, const float* __restrict__ whh1)
{
  int idx = blockIdx.x*256 + threadIdx.x;
  const int N0 = G4H*XW0;          // 2048*1792
  if (idx < N0) {
    int n = idx / XW0, k = idx % XW0;
    wcat0[idx] = (k < EE+DENC) ? wih0[(size_t)n*(EE+DENC) + k] : whh0[(size_t)n*HH + (k - (EE+DENC))];
  } else {
    int j = idx - N0;
    if (j < G4H*XW1) {
      int n = j / XW1, k = j % XW1;
      wcat1[j] = (k < HH) ? wih1[(size_t)n*HH + k] : whh1[(size_t)n*HH + (k - HH)];
    }
  }
}

__global__ __launch_bounds__(256)
void copy_state(float* __restrict__ h, float* __restrict__ c,
                const float* __restrict__ h0, const float* __restrict__ c0,
                float* __restrict__ dec_proj)
{
  int idx = blockIdx.x*256 + threadIdx.x;       // 0..2*BH-1
  h[idx] = h0[idx];
  c[idx] = c0[idx];
  if (idx < BH) dec_proj[idx] = 0.f;
}

extern "C" void kernel_launch(void* const* d_in, const int* in_sizes, int n_in,
                              void* d_out, int out_size, void* d_ws, size_t ws_size,
                              hipStream_t stream) {
  const float* enc_out = (const float*)d_in[0];
  const float* h0      = (const float*)d_in[1];
  const float* c0      = (const float*)d_in[2];
  const int*   targets = (const int*)d_in[3];
  const int*   mask    = (const int*)d_in[4];
  const float* emb     = (const float*)d_in[5];
  const float* W_enc   = (const float*)d_in[6];
  const float* W_dec   = (const float*)d_in[7];
  const float* v       = (const float*)d_in[8];
  const float* b_ih0   = (const float*)d_in[11];
  const float* b_hh0   = (const float*)d_in[12];
  const float* b_ih1   = (const float*)d_in[15];
  const float* b_hh1   = (const float*)d_in[16];
  const float* W_out   = (const float*)d_in[17];
  const float* b_out   = (const float*)d_in[18];
  float* out = (float*)d_out;

  // workspace layout (floats)
  float* ws = (float*)d_ws;
  float* enc_proj = ws;                         size_t o = (size_t)BB*SS*HH;     // 16.8M
  float* wcat0    = ws + o;                     o += (size_t)G4H*XW0;            // 3.67M
  float* wcat1    = ws + o;                     o += (size_t)G4H*XW1;            // 2.10M
  float* xcat0    = ws + o;                     o += (size_t)BB*XW0;
  float* xcat1    = ws + o;                     o += (size_t)BB*XW1;
  float* predcat  = ws + o;                     o += (size_t)BB*PW;
  float* gates    = ws + o;                     o += (size_t)BB*G4H;
  float* dec_proj = ws + o;                     o += (size_t)BB*HH;
  float* hbuf     = ws + o;                     o += (size_t)2*BH;
  float* cbuf     = ws + o;                     o += (size_t)2*BH;
  (void)ws_size; (void)in_sizes; (void)n_in; (void)out_size;

  // setup: concat weights, copy recurrent state, zero dec_proj
  build_wcat<<<(G4H*XW0 + G4H*XW1)/256, 256, 0, stream>>>(wcat0, wcat1,
      (const float*)d_in[9], (const float*)d_in[10], (const float*)d_in[13], (const float*)d_in[14]);
  copy_state<<<(2*BH)/256, 256, 0, stream>>>(hbuf, cbuf, h0, c0, dec_proj);
  // enc_proj = encoder_out @ W_enc.T   (M=32768, N=512, K=1024)
  gemm_tn<64,64,32,false><<<dim3(HH/64, (BB*SS)/64, 1), 256, 0, stream>>>(
      enc_proj, enc_out, W_enc, nullptr, nullptr, BB*SS, HH, DENC, DENC, HH, 0);

  for (int t = 0; t < TT; ++t) {
    // dec_proj += h1 @ W_dec.T (split-K=4 atomic; zeroed beforehand)
    gemm_tn<64,64,32,true><<<dim3(HH/64, BB/64, 4), 256, 0, stream>>>(
        dec_proj, hbuf + BH, W_dec, nullptr, nullptr, BB, HH, HH, HH/4, HH, 0);
    attn_kernel<<<BB, 256, 0, stream>>>(dec_proj, enc_proj, enc_out, v, mask,
        targets, emb, hbuf, xcat0, predcat, t);
    // gates = xcat0 @ wcat0.T + b_ih0 + b_hh0   (M=512, N=2048, K=1792)
    gemm_tn<64,64,32,false><<<dim3(G4H/64, BB/64, 1), 256, 0, stream>>>(
        gates, xcat0, wcat0, b_ih0, b_hh0, BB, G4H, XW0, XW0, G4H, 0);
    lstm_ew0<<<BH/256, 256, 0, stream>>>(gates, hbuf, cbuf, xcat1);
    // gates = xcat1 @ wcat1.T + b_ih1 + b_hh1   (M=512, N=2048, K=1024)
    gemm_tn<64,64,32,false><<<dim3(G4H/64, BB/64, 1), 256, 0, stream>>>(
        gates, xcat1, wcat1, b_ih1, b_hh1, BB, G4H, XW1, XW1, G4H, 0);
    lstm_ew1<<<BH/256, 256, 0, stream>>>(gates, hbuf, cbuf, predcat, dec_proj, out, b_out, t);
    // out[:, t, :] += predcat @ W_out.T  (split-K=8 atomic; initialized with b_out by lstm_ew1)
    gemm_tn<64,64,32,true><<<dim3(VV/64, BB/64, 8), 256, 0, stream>>>(
        out, predcat, W_out, nullptr, nullptr, BB, VV, PW, PW/8, TT*VV, t*VV);
  }
}

// Round 3
// 4309.102 us; speedup vs baseline: 2.4850x; 2.4850x over previous
//
#include <hip/hip_runtime.h>
#include <math.h>

#define BB 512
#define SS 64
#define TT 32
#define VV 128
#define EE 256
#define HH 512
#define DENC 1024
#define BH (BB*HH)
#define XW0 1792   // E + DENC + H
#define XW1 1024   // H + H
#define PW  1792   // H + DENC + E
#define G4H 2048   // 4*H

typedef __attribute__((ext_vector_type(8))) short bf16x8;
typedef __attribute__((ext_vector_type(4))) short bf16x4;
typedef __attribute__((ext_vector_type(4))) float f32x4;

__device__ __forceinline__ float sigf(float x){ return 1.f/(1.f+expf(-x)); }
__device__ __forceinline__ float bf2f(short s){
  return __uint_as_float(((unsigned)(unsigned short)s) << 16);
}
__device__ __forceinline__ short f2bf(float f){
  unsigned u = __float_as_uint(f);
  return (short)((u + 0x7FFF + ((u>>16)&1)) >> 16);   // RNE
}

// C(M,N) = A(M,K)_bf16 @ Bt(N,K)_bf16^T (+bias1+bias2). 4 waves, 16x16x32 MFMA.
// ATOMIC: atomicAdd into fp32 C (split-K, C pre-initialized). OUTBF: write bf16.
template<int BM, int BN, bool ATOMIC, bool OUTBF>
__global__ __launch_bounds__(256)
void mgemm(void* __restrict__ Cv, const short* __restrict__ A, const short* __restrict__ Bt,
           const float* __restrict__ bias1, const float* __restrict__ bias2,
           int K, int kChunk, int ldc, int cOff)
{
  constexpr int LDSK = 40;             // 32 + 8 bf16 pad (keeps 16B align, breaks bank stride)
  constexpr int FI = BM/32, FJ = BN/32;
  __shared__ short As[BM*LDSK];
  __shared__ short Bs[BN*LDSK];
  const int tid = threadIdx.x, lane = tid & 63, wave = tid >> 6;
  const int ml = lane & 15, kq = lane >> 4;
  const int wm = (wave >> 1)*(BM/2), wn = (wave & 1)*(BN/2);
  const int rowBase = blockIdx.y*BM, colBase = blockIdx.x*BN;
  const int k0 = blockIdx.z*kChunk;

  f32x4 acc[FI][FJ];
  #pragma unroll
  for (int i = 0; i < FI; ++i)
    #pragma unroll
    for (int j = 0; j < FJ; ++j)
      acc[i][j] = {0.f, 0.f, 0.f, 0.f};

  for (int kt = k0; kt < k0 + kChunk; kt += 32) {
    #pragma unroll
    for (int i = 0; i < (BM*32)/(256*8); ++i) {
      int t2 = tid + i*256;
      int r = t2 >> 2, c = (t2 & 3)*8;
      *(bf16x8*)&As[r*LDSK + c] = *(const bf16x8*)&A[(size_t)(rowBase+r)*K + kt + c];
    }
    #pragma unroll
    for (int i = 0; i < (BN*32)/(256*8); ++i) {
      int t2 = tid + i*256;
      int r = t2 >> 2, c = (t2 & 3)*8;
      *(bf16x8*)&Bs[r*LDSK + c] = *(const bf16x8*)&Bt[(size_t)(colBase+r)*K + kt + c];
    }
    __syncthreads();
    bf16x8 af[FI], bf[FJ];
    #pragma unroll
    for (int i = 0; i < FI; ++i)
      af[i] = *(const bf16x8*)&As[(wm + i*16 + ml)*LDSK + kq*8];
    #pragma unroll
    for (int j = 0; j < FJ; ++j)
      bf[j] = *(const bf16x8*)&Bs[(wn + j*16 + ml)*LDSK + kq*8];
    #pragma unroll
    for (int i = 0; i < FI; ++i)
      #pragma unroll
      for (int j = 0; j < FJ; ++j)
        acc[i][j] = __builtin_amdgcn_mfma_f32_16x16x32_bf16(af[i], bf[j], acc[i][j], 0, 0, 0);
    __syncthreads();
  }

  #pragma unroll
  for (int i = 0; i < FI; ++i) {
    #pragma unroll
    for (int j = 0; j < FJ; ++j) {
      int n = colBase + wn + j*16 + ml;
      float bv = 0.f;
      if (!ATOMIC) {
        if (bias1) bv += bias1[n];
        if (bias2) bv += bias2[n];
      }
      #pragma unroll
      for (int r = 0; r < 4; ++r) {
        int m = rowBase + wm + i*16 + (lane >> 4)*4 + r;
        float val = acc[i][j][r] + bv;
        if (ATOMIC) {
          atomicAdd(&((float*)Cv)[(size_t)m*ldc + cOff + n], val);
        } else if (OUTBF) {
          ((short*)Cv)[(size_t)m*ldc + cOff + n] = f2bf(val);
        } else {
          ((float*)Cv)[(size_t)m*ldc + cOff + n] = val;
        }
      }
    }
  }
}

// One block per batch b: scores + masked softmax + context; assembles
// xcat0 = [emb | ctx | h0] (bf16) and predcat ctx/emb parts (bf16).
__global__ __launch_bounds__(256)
void attn_kernel(const float* __restrict__ dec_proj, const short* __restrict__ enc_proj,
                 const short* __restrict__ enc_out, const float* __restrict__ vvec,
                 const int* __restrict__ mask, const int* __restrict__ targets,
                 const short* __restrict__ emb, const short* __restrict__ hb,
                 short* __restrict__ xcat0, short* __restrict__ predcat, int t)
{
  const int b = blockIdx.x;
  const int tid = threadIdx.x;
  const int lane = tid & 63, wave = tid >> 6;
  __shared__ float sc[SS];
  __shared__ float wt[SS];

  float dp[8], vr[8];
  #pragma unroll
  for (int i = 0; i < 8; ++i) {
    int hh = lane + 64*i;
    dp[i] = dec_proj[b*HH + hh];
    vr[i] = vvec[hh];
  }
  const short* epb = enc_proj + (size_t)b*SS*HH;
  for (int s = wave*16; s < wave*16 + 16; ++s) {
    float acc = 0.f;
    #pragma unroll
    for (int i = 0; i < 8; ++i) {
      float e = tanhf(dp[i] + bf2f(epb[s*HH + lane + 64*i]));
      acc += e * vr[i];
    }
    #pragma unroll
    for (int off = 32; off; off >>= 1) acc += __shfl_down(acc, off, 64);
    if (lane == 0) sc[s] = acc;
  }
  __syncthreads();
  if (wave == 0) {
    int valid = mask[b*SS + lane];
    float x = valid ? sc[lane] : -INFINITY;
    float mx = x;
    #pragma unroll
    for (int off = 32; off; off >>= 1) mx = fmaxf(mx, __shfl_xor(mx, off, 64));
    float e = valid ? expf(x - mx) : 0.f;
    float sum = e;
    #pragma unroll
    for (int off = 32; off; off >>= 1) sum += __shfl_xor(sum, off, 64);
    wt[lane] = e / sum;
  }
  __syncthreads();
  // context: each thread owns 4 consecutive d
  const short* eob = enc_out + (size_t)b*SS*DENC;
  const int d0 = tid*4;
  float cacc[4] = {0.f, 0.f, 0.f, 0.f};
  for (int s = 0; s < SS; ++s) {
    float w = wt[s];
    bf16x4 ev4 = *(const bf16x4*)&eob[s*DENC + d0];
    #pragma unroll
    for (int k = 0; k < 4; ++k) cacc[k] += w * bf2f(ev4[k]);
  }
  bf16x4 cb;
  #pragma unroll
  for (int k = 0; k < 4; ++k) cb[k] = f2bf(cacc[k]);
  *(bf16x4*)&xcat0[(size_t)b*XW0 + EE + d0] = cb;
  *(bf16x4*)&predcat[(size_t)b*PW + HH + d0] = cb;
  // embedded token (teacher forcing: t==0 -> EOS=2)
  int tok = (t == 0) ? 2 : targets[b*TT + t - 1];
  short ev = emb[tok*EE + tid];
  xcat0[(size_t)b*XW0 + tid] = ev;
  predcat[(size_t)b*PW + HH + DENC + tid] = ev;
  // h0_prev tail
  for (int j = tid; j < HH; j += 256)
    xcat0[(size_t)b*XW0 + EE + DENC + j] = hb[b*HH + j];
}

__global__ __launch_bounds__(256)
void lstm_ew0(const float* __restrict__ gates, short* __restrict__ hb, float* __restrict__ c,
              short* __restrict__ xcat1)
{
  int idx = blockIdx.x*256 + threadIdx.x;
  int b = idx >> 9, hh = idx & 511;
  const float* g = gates + (size_t)b*G4H;
  float gi = g[hh], gf = g[HH+hh], gg = g[2*HH+hh], go = g[3*HH+hh];
  float cp = c[idx];
  float cn = sigf(gf)*cp + sigf(gi)*tanhf(gg);
  float hn = sigf(go)*tanhf(cn);
  c[idx] = cn;
  short hnb = f2bf(hn);
  hb[idx] = hnb;
  xcat1[(size_t)b*XW1 + hh] = hnb;
  xcat1[(size_t)b*XW1 + HH + hh] = hb[BH + idx];  // h1_prev (updated later by ew1)
}

__global__ __launch_bounds__(256)
void lstm_ew1(const float* __restrict__ gates, short* __restrict__ hb, float* __restrict__ c,
              short* __restrict__ predcat, float* __restrict__ out,
              const float* __restrict__ b_out, int t)
{
  int idx = blockIdx.x*256 + threadIdx.x;
  int b = idx >> 9, hh = idx & 511;
  const float* g = gates + (size_t)b*G4H;
  float gi = g[hh], gf = g[HH+hh], gg = g[2*HH+hh], go = g[3*HH+hh];
  float cp = c[BH + idx];
  float cn = sigf(gf)*cp + sigf(gi)*tanhf(gg);
  float hn = sigf(go)*tanhf(cn);
  c[BH + idx] = cn;
  short hnb = f2bf(hn);
  hb[BH + idx] = hnb;
  predcat[(size_t)b*PW + hh] = hnb;
  if (idx < BB*VV) {                              // init out[:, t, :] = b_out
    int b2 = idx >> 7, v2 = idx & 127;
    out[(size_t)(b2*TT + t)*VV + v2] = b_out[v2];
  }
}

__global__ __launch_bounds__(256)
void build_wcat_bf(short* __restrict__ wcat0, short* __restrict__ wcat1,
                   const float* __restrict__ wih0, const float* __restrict__ whh0,
                   const float* __restrict__ wih1, const float* __restrict__ whh1)
{
  int idx = blockIdx.x*256 + threadIdx.x;
  const int N0 = G4H*XW0;
  if (idx < N0) {
    int n = idx / XW0, k = idx % XW0;
    float v = (k < EE+DENC) ? wih0[(size_t)n*(EE+DENC) + k] : whh0[(size_t)n*HH + (k - (EE+DENC))];
    wcat0[idx] = f2bf(v);
  } else {
    int j = idx - N0;
    int n = j / XW1, k = j % XW1;
    float v = (k < HH) ? wih1[(size_t)n*HH + k] : whh1[(size_t)n*HH + (k - HH)];
    wcat1[j] = f2bf(v);
  }
}

__global__ __launch_bounds__(256)
void cvt_encout(short* __restrict__ dst, const float* __restrict__ src)
{
  size_t i8 = ((size_t)blockIdx.x*256 + threadIdx.x)*8;
  float4 a = *(const float4*)&src[i8];
  float4 b = *(const float4*)&src[i8+4];
  bf16x8 o;
  o[0]=f2bf(a.x); o[1]=f2bf(a.y); o[2]=f2bf(a.z); o[3]=f2bf(a.w);
  o[4]=f2bf(b.x); o[5]=f2bf(b.y); o[6]=f2bf(b.z); o[7]=f2bf(b.w);
  *(bf16x8*)&dst[i8] = o;
}

// c0 copy + bf16 conversions of h0, W_dec, W_enc, W_out, emb (2,097,152 elems total)
__global__ __launch_bounds__(256)
void prep_misc(float* __restrict__ cbuf, short* __restrict__ hb,
               short* __restrict__ wdec, short* __restrict__ wenc,
               short* __restrict__ wout, short* __restrict__ embb,
               const float* __restrict__ c0, const float* __restrict__ h0,
               const float* __restrict__ W_dec, const float* __restrict__ W_enc,
               const float* __restrict__ W_out, const float* __restrict__ emb)
{
  int idx = blockIdx.x*256 + threadIdx.x;
  if (idx < 524288) { cbuf[idx] = c0[idx]; return; }
  idx -= 524288;
  if (idx < 524288) { hb[idx] = f2bf(h0[idx]); return; }
  idx -= 524288;
  if (idx < 262144) { wdec[idx] = f2bf(W_dec[idx]); return; }
  idx -= 262144;
  if (idx < 524288) { wenc[idx] = f2bf(W_enc[idx]); return; }
  idx -= 524288;
  if (idx < 229376) { wout[idx] = f2bf(W_out[idx]); return; }
  idx -= 229376;
  embb[idx] = f2bf(emb[idx]);
}

extern "C" void kernel_launch(void* const* d_in, const int* in_sizes, int n_in,
                              void* d_out, int out_size, void* d_ws, size_t ws_size,
                              hipStream_t stream) {
  const float* enc_out = (const float*)d_in[0];
  const float* h0      = (const float*)d_in[1];
  const float* c0      = (const float*)d_in[2];
  const int*   targets = (const int*)d_in[3];
  const int*   mask    = (const int*)d_in[4];
  const float* emb     = (const float*)d_in[5];
  const float* W_enc   = (const float*)d_in[6];
  const float* W_dec   = (const float*)d_in[7];
  const float* v       = (const float*)d_in[8];
  const float* b_ih0   = (const float*)d_in[11];
  const float* b_hh0   = (const float*)d_in[12];
  const float* b_ih1   = (const float*)d_in[15];
  const float* b_hh1   = (const float*)d_in[16];
  const float* b_out   = (const float*)d_in[18];
  float* out = (float*)d_out;

  // workspace layout
  char* ws = (char*)d_ws;
  size_t o = 0;
  short* enc_out_bf = (short*)(ws + o); o += (size_t)BB*SS*DENC*2;   // 67 MB
  short* enc_proj_bf= (short*)(ws + o); o += (size_t)BB*SS*HH*2;     // 33.5 MB
  short* wcat0_bf   = (short*)(ws + o); o += (size_t)G4H*XW0*2;
  short* wcat1_bf   = (short*)(ws + o); o += (size_t)G4H*XW1*2;
  short* wdec_bf    = (short*)(ws + o); o += (size_t)HH*HH*2;
  short* wenc_bf    = (short*)(ws + o); o += (size_t)HH*DENC*2;
  short* wout_bf    = (short*)(ws + o); o += (size_t)VV*PW*2;
  short* emb_bf     = (short*)(ws + o); o += (size_t)VV*EE*2;
  short* xcat0_bf   = (short*)(ws + o); o += (size_t)BB*XW0*2;
  short* xcat1_bf   = (short*)(ws + o); o += (size_t)BB*XW1*2;
  short* predcat_bf = (short*)(ws + o); o += (size_t)BB*PW*2;
  short* hb         = (short*)(ws + o); o += (size_t)2*BH*2;
  float* cbuf       = (float*)(ws + o); o += (size_t)2*BH*4;
  float* gates      = (float*)(ws + o); o += (size_t)BB*G4H*4;
  float* dec_proj   = (float*)(ws + o); o += (size_t)BB*HH*4;
  (void)ws_size; (void)in_sizes; (void)n_in; (void)out_size;

  cvt_encout<<<16384, 256, 0, stream>>>(enc_out_bf, enc_out);
  build_wcat_bf<<<22528, 256, 0, stream>>>(wcat0_bf, wcat1_bf,
      (const float*)d_in[9], (const float*)d_in[10], (const float*)d_in[13], (const float*)d_in[14]);
  prep_misc<<<8192, 256, 0, stream>>>(cbuf, hb, wdec_bf, wenc_bf, wout_bf, emb_bf,
      c0, h0, W_dec, W_enc, (const float*)d_in[17], emb);
  // enc_proj = enc_out @ W_enc.T  (M=32768, N=512, K=1024) -> bf16
  mgemm<128,128,false,true><<<dim3(HH/128, (BB*SS)/128, 1), 256, 0, stream>>>(
      enc_proj_bf, enc_out_bf, wenc_bf, nullptr, nullptr, DENC, DENC, HH, 0);

  for (int t = 0; t < TT; ++t) {
    // dec_proj = h1 @ W_dec.T  (M=512, N=512, K=512) fp32 out
    mgemm<64,64,false,false><<<dim3(HH/64, BB/64, 1), 256, 0, stream>>>(
        dec_proj, hb + BH, wdec_bf, nullptr, nullptr, HH, HH, HH, 0);
    attn_kernel<<<BB, 256, 0, stream>>>(dec_proj, enc_proj_bf, enc_out_bf, v, mask,
        targets, emb_bf, hb, xcat0_bf, predcat_bf, t);
    // gates = xcat0 @ wcat0.T + b_ih0 + b_hh0  (M=512, N=2048, K=1792)
    mgemm<64,64,false,false><<<dim3(G4H/64, BB/64, 1), 256, 0, stream>>>(
        gates, xcat0_bf, wcat0_bf, b_ih0, b_hh0, XW0, XW0, G4H, 0);
    lstm_ew0<<<BH/256, 256, 0, stream>>>(gates, hb, cbuf, xcat1_bf);
    // gates = xcat1 @ wcat1.T + b_ih1 + b_hh1  (M=512, N=2048, K=1024)
    mgemm<64,64,false,false><<<dim3(G4H/64, BB/64, 1), 256, 0, stream>>>(
        gates, xcat1_bf, wcat1_bf, b_ih1, b_hh1, XW1, XW1, G4H, 0);
    lstm_ew1<<<BH/256, 256, 0, stream>>>(gates, hb, cbuf, predcat_bf, out, b_out, t);
    // out[:, t, :] += predcat @ W_out.T  (split-K=4 atomic; b_out init by lstm_ew1)
    mgemm<64,64,true,false><<<dim3(VV/64, BB/64, 4), 256, 0, stream>>>(
        out, predcat_bf, wout_bf, nullptr, nullptr, PW, PW/4, TT*VV, t*VV);
  }
}

// Round 4
// 4278.981 us; speedup vs baseline: 2.5025x; 1.0070x over previous
//
#include <hip/hip_runtime.h>
#include <math.h>

#define BB 512
#define SS 64
#define TT 32
#define VV 128
#define EE 256
#define HH 512
#define DENC 1024
#define BH (BB*HH)
#define XW0 1792   // E + DENC + H
#define XW1 1024   // H + H
#define PW  1792   // H + DENC + E
#define G4H 2048   // 4*H

typedef __attribute__((ext_vector_type(8))) short bf16x8;
typedef __attribute__((ext_vector_type(4))) short bf16x4;
typedef __attribute__((ext_vector_type(4))) float f32x4;

__device__ __forceinline__ float sigf(float x){ return 1.f/(1.f+expf(-x)); }
__device__ __forceinline__ float bf2f(short s){
  return __uint_as_float(((unsigned)(unsigned short)s) << 16);
}
__device__ __forceinline__ short f2bf(float f){
  unsigned u = __float_as_uint(f);
  return (short)((u + 0x7FFF + ((u>>16)&1)) >> 16);   // RNE
}

// 64x64 tile bf16 MFMA core: acc += A(rowBase.., K) @ Bt(colBase.., K)^T
__device__ __forceinline__ void gemm64_core(short* As, short* Bs,
    const short* __restrict__ A, const short* __restrict__ Bt, int K,
    int rowBase, int colBase, int tid, f32x4 acc[2][2])
{
  const int lane = tid & 63, wave = tid >> 6;
  const int ml = lane & 15, kq = lane >> 4;
  const int wm = (wave >> 1)*32, wn = (wave & 1)*32;
  const int r = tid >> 2, c = (tid & 3)*8;
  for (int kt = 0; kt < K; kt += 32) {
    *(bf16x8*)&As[r*40 + c] = *(const bf16x8*)&A[(size_t)(rowBase+r)*K + kt + c];
    *(bf16x8*)&Bs[r*40 + c] = *(const bf16x8*)&Bt[(size_t)(colBase+r)*K + kt + c];
    __syncthreads();
    bf16x8 af0 = *(const bf16x8*)&As[(wm + ml)*40 + kq*8];
    bf16x8 af1 = *(const bf16x8*)&As[(wm + 16 + ml)*40 + kq*8];
    bf16x8 bf0 = *(const bf16x8*)&Bs[(wn + ml)*40 + kq*8];
    bf16x8 bf1 = *(const bf16x8*)&Bs[(wn + 16 + ml)*40 + kq*8];
    acc[0][0] = __builtin_amdgcn_mfma_f32_16x16x32_bf16(af0, bf0, acc[0][0], 0,0,0);
    acc[0][1] = __builtin_amdgcn_mfma_f32_16x16x32_bf16(af0, bf1, acc[0][1], 0,0,0);
    acc[1][0] = __builtin_amdgcn_mfma_f32_16x16x32_bf16(af1, bf0, acc[1][0], 0,0,0);
    acc[1][1] = __builtin_amdgcn_mfma_f32_16x16x32_bf16(af1, bf1, acc[1][1], 0,0,0);
    __syncthreads();
  }
}

// gates GEMM (interleaved cols n=4*h+gate) + fused LSTM cell epilogue.
// layer0: d1=xcat1_cur(+0), d2=xcat0_next(+1280). layer1: d1=xcat1_next(+512), d2=predcat, d3=hb.
__global__ __launch_bounds__(256)
void gates_fused(const short* __restrict__ A, const short* __restrict__ W,
                 const float* __restrict__ bias, float* __restrict__ cb,
                 short* __restrict__ d1, short* __restrict__ d2, short* __restrict__ d3,
                 int K, int layer)
{
  __shared__ __align__(16) char smem[64*68*4];
  short* As = (short*)smem;
  short* Bs = (short*)(smem + 5120);
  float* Ct = (float*)smem;
  const int tid = threadIdx.x;
  const int rowBase = blockIdx.y*64, colBase = blockIdx.x*64;
  f32x4 acc[2][2];
  #pragma unroll
  for (int i = 0; i < 2; ++i)
    #pragma unroll
    for (int j = 0; j < 2; ++j) acc[i][j] = {0.f,0.f,0.f,0.f};
  gemm64_core(As, Bs, A, W, K, rowBase, colBase, tid, acc);
  const int lane = tid & 63, wave = tid >> 6, ml = lane & 15, kq = lane >> 4;
  const int wm = (wave >> 1)*32, wn = (wave & 1)*32;
  float bj0 = bias[colBase + wn + ml];
  float bj1 = bias[colBase + wn + 16 + ml];
  #pragma unroll
  for (int i = 0; i < 2; ++i)
    #pragma unroll
    for (int j = 0; j < 2; ++j)
      #pragma unroll
      for (int r2 = 0; r2 < 4; ++r2)
        Ct[(wm + i*16 + kq*4 + r2)*68 + wn + j*16 + ml] = acc[i][j][r2] + (j ? bj1 : bj0);
  __syncthreads();
  #pragma unroll
  for (int kk = 0; kk < 4; ++kk) {
    int cidx = tid + kk*256;
    int m = cidx >> 4, hl = cidx & 15;
    float4 gv = *(float4*)&Ct[m*68 + hl*4];     // i,f,g,o
    int b_ = rowBase + m, h_ = (colBase >> 2) + hl;
    float cp = cb[b_*HH + h_];
    float cn = sigf(gv.y)*cp + sigf(gv.x)*tanhf(gv.z);
    float hn = sigf(gv.w)*tanhf(cn);
    cb[b_*HH + h_] = cn;
    short hb16 = f2bf(hn);
    if (layer == 0) {
      d1[(size_t)b_*XW1 + h_] = hb16;
      d2[(size_t)b_*XW0 + h_] = hb16;
    } else {
      d1[(size_t)b_*XW1 + h_] = hb16;
      d2[(size_t)b_*PW  + h_] = hb16;
      d3[(size_t)b_*HH  + h_] = hb16;
    }
  }
}

// blocks 0..63: dec_proj = hb @ wdec.T (fp32). blocks 64..79: out[:,tOut,:] = predcat @ wout.T + b_out.
__global__ __launch_bounds__(256)
void combo(float* __restrict__ dec_proj, const short* __restrict__ hb, const short* __restrict__ wdec,
           float* __restrict__ out, const short* __restrict__ predcat, const short* __restrict__ wout,
           const float* __restrict__ b_out, int tOut, int doDec)
{
  __shared__ __align__(16) short As[64*40];
  __shared__ __align__(16) short Bs[64*40];
  const int tid = threadIdx.x;
  f32x4 acc[2][2];
  #pragma unroll
  for (int i = 0; i < 2; ++i)
    #pragma unroll
    for (int j = 0; j < 2; ++j) acc[i][j] = {0.f,0.f,0.f,0.f};
  const int lane = tid & 63, wave = tid >> 6, ml = lane & 15, kq = lane >> 4;
  const int wm = (wave >> 1)*32, wn = (wave & 1)*32;
  if (blockIdx.x < 64) {
    if (!doDec) return;
    int rowBase = (blockIdx.x >> 3)*64, colBase = (blockIdx.x & 7)*64;
    gemm64_core(As, Bs, hb, wdec, HH, rowBase, colBase, tid, acc);
    #pragma unroll
    for (int i = 0; i < 2; ++i)
      #pragma unroll
      for (int j = 0; j < 2; ++j)
        #pragma unroll
        for (int r2 = 0; r2 < 4; ++r2) {
          int m = rowBase + wm + i*16 + kq*4 + r2;
          int n = colBase + wn + j*16 + ml;
          dec_proj[(size_t)m*HH + n] = acc[i][j][r2];
        }
  } else {
    if (tOut < 0) return;
    int idx = blockIdx.x - 64;
    int rowBase = (idx >> 1)*64, colBase = (idx & 1)*64;
    gemm64_core(As, Bs, predcat, wout, PW, rowBase, colBase, tid, acc);
    #pragma unroll
    for (int i = 0; i < 2; ++i)
      #pragma unroll
      for (int j = 0; j < 2; ++j) {
        int n = colBase + wn + j*16 + ml;
        float bv = b_out[n];
        #pragma unroll
        for (int r2 = 0; r2 < 4; ++r2) {
          int m = rowBase + wm + i*16 + kq*4 + r2;
          out[(size_t)m*(TT*VV) + tOut*VV + n] = acc[i][j][r2] + bv;
        }
      }
  }
}

// enc_proj big GEMM (128x128 tile), bf16 out
template<int BM, int BN>
__global__ __launch_bounds__(256)
void mgemm_bf(short* __restrict__ Cv, const short* __restrict__ A, const short* __restrict__ Bt,
              int K, int ldc)
{
  constexpr int LDSK = 40;
  constexpr int FI = BM/32, FJ = BN/32;
  __shared__ short As[BM*LDSK];
  __shared__ short Bs[BN*LDSK];
  const int tid = threadIdx.x, lane = tid & 63, wave = tid >> 6;
  const int ml = lane & 15, kq = lane >> 4;
  const int wm = (wave >> 1)*(BM/2), wn = (wave & 1)*(BN/2);
  const int rowBase = blockIdx.y*BM, colBase = blockIdx.x*BN;
  f32x4 acc[FI][FJ];
  #pragma unroll
  for (int i = 0; i < FI; ++i)
    #pragma unroll
    for (int j = 0; j < FJ; ++j) acc[i][j] = {0.f,0.f,0.f,0.f};
  for (int kt = 0; kt < K; kt += 32) {
    #pragma unroll
    for (int i = 0; i < (BM*32)/(256*8); ++i) {
      int t2 = tid + i*256;
      int r = t2 >> 2, c = (t2 & 3)*8;
      *(bf16x8*)&As[r*LDSK + c] = *(const bf16x8*)&A[(size_t)(rowBase+r)*K + kt + c];
    }
    #pragma unroll
    for (int i = 0; i < (BN*32)/(256*8); ++i) {
      int t2 = tid + i*256;
      int r = t2 >> 2, c = (t2 & 3)*8;
      *(bf16x8*)&Bs[r*LDSK + c] = *(const bf16x8*)&Bt[(size_t)(colBase+r)*K + kt + c];
    }
    __syncthreads();
    bf16x8 af[FI], bfr[FJ];
    #pragma unroll
    for (int i = 0; i < FI; ++i) af[i] = *(const bf16x8*)&As[(wm + i*16 + ml)*LDSK + kq*8];
    #pragma unroll
    for (int j = 0; j < FJ; ++j) bfr[j] = *(const bf16x8*)&Bs[(wn + j*16 + ml)*LDSK + kq*8];
    #pragma unroll
    for (int i = 0; i < FI; ++i)
      #pragma unroll
      for (int j = 0; j < FJ; ++j)
        acc[i][j] = __builtin_amdgcn_mfma_f32_16x16x32_bf16(af[i], bfr[j], acc[i][j], 0,0,0);
    __syncthreads();
  }
  #pragma unroll
  for (int i = 0; i < FI; ++i)
    #pragma unroll
    for (int j = 0; j < FJ; ++j) {
      int n = colBase + wn + j*16 + ml;
      #pragma unroll
      for (int r2 = 0; r2 < 4; ++r2) {
        int m = rowBase + wm + i*16 + kq*4 + r2;
        Cv[(size_t)m*ldc + n] = f2bf(acc[i][j][r2]);
      }
    }
}

// attention: scores + masked softmax + context; writes ctx/emb into xcat0_cur & predcat.
__global__ __launch_bounds__(256)
void attn_kernel(const float* __restrict__ dec_proj, const short* __restrict__ enc_proj,
                 const short* __restrict__ enc_out, const float* __restrict__ vvec,
                 const int* __restrict__ mask, const int* __restrict__ targets,
                 const short* __restrict__ emb, short* __restrict__ xcat0,
                 short* __restrict__ predcat, int t)
{
  const int b = blockIdx.x;
  const int tid = threadIdx.x;
  const int lane = tid & 63, wave = tid >> 6;
  __shared__ float sc[SS];
  __shared__ float wt[SS];
  float dp[8], vr[8];
  #pragma unroll
  for (int i = 0; i < 8; ++i) {
    int hh = lane + 64*i;
    dp[i] = dec_proj[b*HH + hh];
    vr[i] = vvec[hh];
  }
  const short* epb = enc_proj + (size_t)b*SS*HH;
  for (int s = wave*16; s < wave*16 + 16; ++s) {
    float acc = 0.f;
    #pragma unroll
    for (int i = 0; i < 8; ++i) {
      float e = tanhf(dp[i] + bf2f(epb[s*HH + lane + 64*i]));
      acc += e * vr[i];
    }
    #pragma unroll
    for (int off = 32; off; off >>= 1) acc += __shfl_down(acc, off, 64);
    if (lane == 0) sc[s] = acc;
  }
  __syncthreads();
  if (wave == 0) {
    int valid = mask[b*SS + lane];
    float x = valid ? sc[lane] : -INFINITY;
    float mx = x;
    #pragma unroll
    for (int off = 32; off; off >>= 1) mx = fmaxf(mx, __shfl_xor(mx, off, 64));
    float e = valid ? expf(x - mx) : 0.f;
    float sum = e;
    #pragma unroll
    for (int off = 32; off; off >>= 1) sum += __shfl_xor(sum, off, 64);
    wt[lane] = e / sum;
  }
  __syncthreads();
  const short* eob = enc_out + (size_t)b*SS*DENC;
  const int d0 = tid*4;
  float cacc[4] = {0.f,0.f,0.f,0.f};
  for (int s = 0; s < SS; ++s) {
    float w = wt[s];
    bf16x4 ev4 = *(const bf16x4*)&eob[s*DENC + d0];
    #pragma unroll
    for (int k = 0; k < 4; ++k) cacc[k] += w * bf2f(ev4[k]);
  }
  bf16x4 cbv;
  #pragma unroll
  for (int k = 0; k < 4; ++k) cbv[k] = f2bf(cacc[k]);
  *(bf16x4*)&xcat0[(size_t)b*XW0 + EE + d0] = cbv;
  *(bf16x4*)&predcat[(size_t)b*PW + HH + d0] = cbv;
  int tok = (t == 0) ? 2 : targets[b*TT + t - 1];
  short ev = emb[tok*EE + tid];
  xcat0[(size_t)b*XW0 + tid] = ev;
  predcat[(size_t)b*PW + HH + DENC + tid] = ev;
}

// interleaved (n = 4*h + gate) bf16 weight concat
__global__ __launch_bounds__(256)
void build_wcat_bf(short* __restrict__ wcat0, short* __restrict__ wcat1,
                   const float* __restrict__ wih0, const float* __restrict__ whh0,
                   const float* __restrict__ wih1, const float* __restrict__ whh1)
{
  int idx = blockIdx.x*256 + threadIdx.x;
  const int N0 = G4H*XW0;
  if (idx < N0) {
    int n = idx / XW0, k = idx % XW0;
    int row = (n & 3)*HH + (n >> 2);
    float v = (k < EE+DENC) ? wih0[(size_t)row*(EE+DENC) + k] : whh0[(size_t)row*HH + (k - (EE+DENC))];
    wcat0[idx] = f2bf(v);
  } else {
    int j = idx - N0;
    int n = j / XW1, k = j % XW1;
    int row = (n & 3)*HH + (n >> 2);
    float v = (k < HH) ? wih1[(size_t)row*HH + k] : whh1[(size_t)row*HH + (k - HH)];
    wcat1[j] = f2bf(v);
  }
}

__global__ __launch_bounds__(256)
void cvt_encout(short* __restrict__ dst, const float* __restrict__ src)
{
  size_t i8 = ((size_t)blockIdx.x*256 + threadIdx.x)*8;
  float4 a = *(const float4*)&src[i8];
  float4 b = *(const float4*)&src[i8+4];
  bf16x8 o;
  o[0]=f2bf(a.x); o[1]=f2bf(a.y); o[2]=f2bf(a.z); o[3]=f2bf(a.w);
  o[4]=f2bf(b.x); o[5]=f2bf(b.y); o[6]=f2bf(b.z); o[7]=f2bf(b.w);
  *(bf16x8*)&dst[i8] = o;
}

__global__ __launch_bounds__(256)
void prep_misc(float* __restrict__ cbuf, short* __restrict__ xcat0a, short* __restrict__ xcat1a,
               short* __restrict__ hb, short* __restrict__ wdec, short* __restrict__ wenc,
               short* __restrict__ wout, short* __restrict__ embb,
               float* __restrict__ bias0i, float* __restrict__ bias1i,
               const float* __restrict__ c0, const float* __restrict__ h0,
               const float* __restrict__ W_dec, const float* __restrict__ W_enc,
               const float* __restrict__ W_out, const float* __restrict__ emb,
               const float* __restrict__ b_ih0, const float* __restrict__ b_hh0,
               const float* __restrict__ b_ih1, const float* __restrict__ b_hh1)
{
  int idx = blockIdx.x*256 + threadIdx.x;
  if (idx < 524288) { cbuf[idx] = c0[idx]; return; }
  idx -= 524288;
  if (idx < 262144) {                         // h0 layer0 -> xcat0a tail
    int b = idx >> 9, h = idx & 511;
    xcat0a[(size_t)b*XW0 + EE + DENC + h] = f2bf(h0[idx]);
    return;
  }
  idx -= 262144;
  if (idx < 262144) {                         // h0 layer1 -> xcat1a 2nd half + hb
    int b = idx >> 9, h = idx & 511;
    short v = f2bf(h0[BH + idx]);
    xcat1a[(size_t)b*XW1 + HH + h] = v;
    hb[idx] = v;
    return;
  }
  idx -= 262144;
  if (idx < 262144) { wdec[idx] = f2bf(W_dec[idx]); return; }
  idx -= 262144;
  if (idx < 524288) { wenc[idx] = f2bf(W_enc[idx]); return; }
  idx -= 524288;
  if (idx < 229376) { wout[idx] = f2bf(W_out[idx]); return; }
  idx -= 229376;
  if (idx < 32768)  { embb[idx] = f2bf(emb[idx]); return; }
  idx -= 32768;
  if (idx < 2048) {
    int row = (idx & 3)*HH + (idx >> 2);
    bias0i[idx] = b_ih0[row] + b_hh0[row];
    return;
  }
  idx -= 2048;
  {
    int row = (idx & 3)*HH + (idx >> 2);
    bias1i[idx] = b_ih1[row] + b_hh1[row];
  }
}

extern "C" void kernel_launch(void* const* d_in, const int* in_sizes, int n_in,
                              void* d_out, int out_size, void* d_ws, size_t ws_size,
                              hipStream_t stream) {
  const float* enc_out = (const float*)d_in[0];
  const float* h0      = (const float*)d_in[1];
  const float* c0      = (const float*)d_in[2];
  const int*   targets = (const int*)d_in[3];
  const int*   mask    = (const int*)d_in[4];
  const float* emb     = (const float*)d_in[5];
  const float* W_enc   = (const float*)d_in[6];
  const float* W_dec   = (const float*)d_in[7];
  const float* v       = (const float*)d_in[8];
  const float* b_ih0   = (const float*)d_in[11];
  const float* b_hh0   = (const float*)d_in[12];
  const float* b_ih1   = (const float*)d_in[15];
  const float* b_hh1   = (const float*)d_in[16];
  const float* b_out   = (const float*)d_in[18];
  float* out = (float*)d_out;

  char* ws = (char*)d_ws;
  size_t o = 0;
  short* enc_out_bf = (short*)(ws + o); o += (size_t)BB*SS*DENC*2;
  short* enc_proj_bf= (short*)(ws + o); o += (size_t)BB*SS*HH*2;
  short* wcat0i     = (short*)(ws + o); o += (size_t)G4H*XW0*2;
  short* wcat1i     = (short*)(ws + o); o += (size_t)G4H*XW1*2;
  short* wdec_bf    = (short*)(ws + o); o += (size_t)HH*HH*2;
  short* wenc_bf    = (short*)(ws + o); o += (size_t)HH*DENC*2;
  short* wout_bf    = (short*)(ws + o); o += (size_t)VV*PW*2;
  short* emb_bf     = (short*)(ws + o); o += (size_t)VV*EE*2;
  short* xcat0a     = (short*)(ws + o); o += (size_t)BB*XW0*2;
  short* xcat0b     = (short*)(ws + o); o += (size_t)BB*XW0*2;
  short* xcat1a     = (short*)(ws + o); o += (size_t)BB*XW1*2;
  short* xcat1b     = (short*)(ws + o); o += (size_t)BB*XW1*2;
  short* predcat_bf = (short*)(ws + o); o += (size_t)BB*PW*2;
  short* hb         = (short*)(ws + o); o += (size_t)BH*2;
  float* cbuf       = (float*)(ws + o); o += (size_t)2*BH*4;
  float* dec_proj   = (float*)(ws + o); o += (size_t)BB*HH*4;
  float* bias0i     = (float*)(ws + o); o += (size_t)G4H*4;
  float* bias1i     = (float*)(ws + o); o += (size_t)G4H*4;
  (void)ws_size; (void)in_sizes; (void)n_in; (void)out_size;

  cvt_encout<<<16384, 256, 0, stream>>>(enc_out_bf, enc_out);
  build_wcat_bf<<<22528, 256, 0, stream>>>(wcat0i, wcat1i,
      (const float*)d_in[9], (const float*)d_in[10], (const float*)d_in[13], (const float*)d_in[14]);
  prep_misc<<<8208, 256, 0, stream>>>(cbuf, xcat0a, xcat1a, hb, wdec_bf, wenc_bf, wout_bf, emb_bf,
      bias0i, bias1i, c0, h0, W_dec, W_enc, (const float*)d_in[17], emb,
      b_ih0, b_hh0, b_ih1, b_hh1);
  mgemm_bf<128,128><<<dim3(HH/128, (BB*SS)/128, 1), 256, 0, stream>>>(
      enc_proj_bf, enc_out_bf, wenc_bf, DENC, HH);

  short* xc0[2] = {xcat0a, xcat0b};
  short* xc1[2] = {xcat1a, xcat1b};
  for (int t = 0; t < TT; ++t) {
    combo<<<80, 256, 0, stream>>>(dec_proj, hb, wdec_bf, out, predcat_bf, wout_bf, b_out, t-1, 1);
    attn_kernel<<<BB, 256, 0, stream>>>(dec_proj, enc_proj_bf, enc_out_bf, v, mask,
        targets, emb_bf, xc0[t&1], predcat_bf, t);
    gates_fused<<<dim3(G4H/64, BB/64), 256, 0, stream>>>(
        xc0[t&1], wcat0i, bias0i, cbuf, xc1[t&1], xc0[(t+1)&1] + EE + DENC, (short*)nullptr, XW0, 0);
    gates_fused<<<dim3(G4H/64, BB/64), 256, 0, stream>>>(
        xc1[t&1], wcat1i, bias1i, cbuf + BH, xc1[(t+1)&1] + HH, predcat_bf, hb, XW1, 1);
  }
  combo<<<80, 256, 0, stream>>>(dec_proj, hb, wdec_bf, out, predcat_bf, wout_bf, b_out, TT-1, 0);
}

// Round 5
// 2868.152 us; speedup vs baseline: 3.7335x; 1.4919x over previous
//
#include <hip/hip_runtime.h>
#include <math.h>

#define BB 512
#define SS 64
#define TT 32
#define VV 128
#define EE 256
#define HH 512
#define DENC 1024
#define BH (BB*HH)
#define XW0 1792   // E + DENC + H
#define XW1 1024   // H + H
#define PW  1792   // H + DENC + E
#define G4H 2048   // 4*H

typedef __attribute__((ext_vector_type(8))) short bf16x8;
typedef __attribute__((ext_vector_type(4))) short bf16x4;
typedef __attribute__((ext_vector_type(4))) float f32x4;

__device__ __forceinline__ float sigf(float x){ return 1.f/(1.f+expf(-x)); }
__device__ __forceinline__ float bf2f(short s){
  return __uint_as_float(((unsigned)(unsigned short)s) << 16);
}
__device__ __forceinline__ short f2bf(float f){
  unsigned u = __float_as_uint(f);
  return (short)((u + 0x7FFF + ((u>>16)&1)) >> 16);   // RNE
}
__device__ __forceinline__ float tanh_fast(float x){
  x = fminf(fmaxf(x, -15.f), 15.f);
  float e = __expf(2.f*x);
  return (e - 1.f) / (e + 1.f);
}

// Double-buffered pipelined bf16 MFMA GEMM core. BK=64, one barrier per iter.
// LDS row stride 72 shorts (2-way bank aliasing only). K must be a multiple of 64.
// Wave w computes tile (BM/2)x(BN/2) at wm=(w>>1)*(BM/2), wn=(w&1)*(BN/2).
template<int BM, int BN>
struct GemmPipe {
  static constexpr int LA = 72;
  static __device__ __forceinline__ void run(short* Asb, short* Bsb,
      const short* __restrict__ A, const short* __restrict__ Bt, int K,
      int rowBase, int colBase, int tid, f32x4 acc[BM/32][BN/32])
  {
    constexpr int FI = BM/32, FJ = BN/32, ACH = BM/32, BCH = BN/32;
    const int lane = tid & 63, wave = tid >> 6;
    const int ml = lane & 15, kq = lane >> 4;
    const int wm = (wave >> 1)*(BM/2), wn = (wave & 1)*(BN/2);
    const int arow = (tid*ACH) >> 3, acol = ((tid*ACH) & 7)*8;
    const int brow = (tid*BCH) >> 3, bcol = ((tid*BCH) & 7)*8;
    const short* Ap = A + (size_t)(rowBase+arow)*K + acol;
    const short* Bp = Bt + (size_t)(colBase+brow)*K + bcol;
    bf16x8 ar[ACH], br[BCH];
    #pragma unroll
    for (int c = 0; c < ACH; ++c) ar[c] = *(const bf16x8*)(Ap + c*8);
    #pragma unroll
    for (int c = 0; c < BCH; ++c) br[c] = *(const bf16x8*)(Bp + c*8);
    const int nIter = K >> 6;
    for (int i = 0; i < nIter; ++i) {
      short* Ab = Asb + (i&1)*(BM*LA);
      short* Bb = Bsb + (i&1)*(BN*LA);
      #pragma unroll
      for (int c = 0; c < ACH; ++c) *(bf16x8*)&Ab[arow*LA + acol + c*8] = ar[c];
      #pragma unroll
      for (int c = 0; c < BCH; ++c) *(bf16x8*)&Bb[brow*LA + bcol + c*8] = br[c];
      __syncthreads();
      if (i+1 < nIter) {
        const short* An = Ap + (size_t)(i+1)*64;
        const short* Bn = Bp + (size_t)(i+1)*64;
        #pragma unroll
        for (int c = 0; c < ACH; ++c) ar[c] = *(const bf16x8*)(An + c*8);
        #pragma unroll
        for (int c = 0; c < BCH; ++c) br[c] = *(const bf16x8*)(Bn + c*8);
      }
      #pragma unroll
      for (int kh = 0; kh < 2; ++kh) {
        bf16x8 af[FI], bfv[FJ];
        #pragma unroll
        for (int ii = 0; ii < FI; ++ii)
          af[ii] = *(const bf16x8*)&Ab[(wm + ii*16 + ml)*LA + kh*32 + kq*8];
        #pragma unroll
        for (int jj = 0; jj < FJ; ++jj)
          bfv[jj] = *(const bf16x8*)&Bb[(wn + jj*16 + ml)*LA + kh*32 + kq*8];
        #pragma unroll
        for (int ii = 0; ii < FI; ++ii)
          #pragma unroll
          for (int jj = 0; jj < FJ; ++jj)
            acc[ii][jj] = __builtin_amdgcn_mfma_f32_16x16x32_bf16(af[ii], bfv[jj], acc[ii][jj], 0,0,0);
      }
    }
    __syncthreads();
  }
};

// gates GEMM (interleaved cols n=4*h+gate) + fused LSTM cell epilogue.
__global__ __launch_bounds__(256)
void gates_fused(const short* __restrict__ A, const short* __restrict__ W,
                 const float* __restrict__ bias, float* __restrict__ cb,
                 short* __restrict__ d1, short* __restrict__ d2, short* __restrict__ d3,
                 int K, int layer)
{
  __shared__ __align__(16) char smem[36864];
  short* As = (short*)smem;
  short* Bs = (short*)(smem + 18432);
  const int tid = threadIdx.x;
  const int rowBase = blockIdx.y*64, colBase = blockIdx.x*64;
  f32x4 acc[2][2];
  #pragma unroll
  for (int i = 0; i < 2; ++i)
    #pragma unroll
    for (int j = 0; j < 2; ++j) acc[i][j] = {0.f,0.f,0.f,0.f};
  GemmPipe<64,64>::run(As, Bs, A, W, K, rowBase, colBase, tid, acc);
  const int lane = tid & 63, wave = tid >> 6, ml = lane & 15, kq = lane >> 4;
  const int wm = (wave >> 1)*32, wn = (wave & 1)*32;
  float* Ct = (float*)smem;                    // 64*68*4 = 17408 <= 18432
  float bj0 = bias[colBase + wn + ml];
  float bj1 = bias[colBase + wn + 16 + ml];
  #pragma unroll
  for (int ii = 0; ii < 2; ++ii)
    #pragma unroll
    for (int jj = 0; jj < 2; ++jj)
      #pragma unroll
      for (int r2 = 0; r2 < 4; ++r2)
        Ct[(wm + ii*16 + kq*4 + r2)*68 + wn + jj*16 + ml] = acc[ii][jj][r2] + (jj ? bj1 : bj0);
  __syncthreads();
  #pragma unroll
  for (int kk = 0; kk < 4; ++kk) {
    int cidx = tid + kk*256;
    int m = cidx >> 4, hl = cidx & 15;
    float4 gv = *(float4*)&Ct[m*68 + hl*4];    // i,f,g,o
    int b_ = rowBase + m, h_ = (colBase >> 2) + hl;
    float cp = cb[b_*HH + h_];
    float cn = sigf(gv.y)*cp + sigf(gv.x)*tanhf(gv.z);
    float hn = sigf(gv.w)*tanhf(cn);
    cb[b_*HH + h_] = cn;
    short hb16 = f2bf(hn);
    if (layer == 0) {
      d1[(size_t)b_*XW1 + h_] = hb16;
      d2[(size_t)b_*XW0 + h_] = hb16;
    } else {
      d1[(size_t)b_*XW1 + h_] = hb16;
      d2[(size_t)b_*PW  + h_] = hb16;
      d3[(size_t)b_*HH  + h_] = hb16;
    }
  }
}

// blocks 0..255: attention for b = 2*blk, 2*blk+1 (dec_proj computed in-kernel from wdecT)
// blocks 256..271: out[:, t-1, :] = predprev @ wout.T + b_out
__global__ __launch_bounds__(256)
void attn_out(const short* __restrict__ enc_proj, const short* __restrict__ enc_out,
              const float* __restrict__ vvec, const int* __restrict__ mask,
              const int* __restrict__ targets, const short* __restrict__ embb,
              const short* __restrict__ hb, const short* __restrict__ wdecT,
              short* __restrict__ xcat0, short* __restrict__ predcat,
              const short* __restrict__ predprev, const short* __restrict__ wout,
              const float* __restrict__ b_out, float* __restrict__ out, int t)
{
  __shared__ __align__(16) char smem[36864];
  const int tid = threadIdx.x;
  if (blockIdx.x >= 256) {
    if (t == 0) return;
    short* As = (short*)smem;
    short* Bs = (short*)(smem + 18432);
    int idx = blockIdx.x - 256;
    int rowBase = (idx >> 1)*64, colBase = (idx & 1)*64;
    f32x4 acc[2][2];
    #pragma unroll
    for (int i = 0; i < 2; ++i)
      #pragma unroll
      for (int j = 0; j < 2; ++j) acc[i][j] = {0.f,0.f,0.f,0.f};
    GemmPipe<64,64>::run(As, Bs, predprev, wout, PW, rowBase, colBase, tid, acc);
    const int lane = tid & 63, wave = tid >> 6, ml = lane & 15, kq = lane >> 4;
    const int wm = (wave >> 1)*32, wn = (wave & 1)*32;
    #pragma unroll
    for (int ii = 0; ii < 2; ++ii)
      #pragma unroll
      for (int jj = 0; jj < 2; ++jj) {
        int n = colBase + wn + jj*16 + ml;
        float bv = b_out[n];
        #pragma unroll
        for (int r2 = 0; r2 < 4; ++r2) {
          int m = rowBase + wm + ii*16 + kq*4 + r2;
          out[(size_t)m*(TT*VV) + (size_t)(t-1)*VV + n] = acc[ii][jj][r2] + bv;
        }
      }
    return;
  }
  if (t >= TT) return;
  const int b0 = blockIdx.x*2;
  float* hbf = (float*)smem;                  // [2][512]
  float* dps = (float*)(smem + 4096);         // [ksel][b][512] = 4x512
  float* vvf = (float*)(smem + 12288);        // [512]
  float* sc  = (float*)(smem + 14336);        // [2][64]
  float* wt  = (float*)(smem + 14848);        // [2][64]
  {
    bf16x4 h4 = *(const bf16x4*)&hb[(size_t)b0*HH + tid*4];
    #pragma unroll
    for (int j = 0; j < 4; ++j) hbf[tid*4 + j] = bf2f(h4[j]);
    vvf[tid] = vvec[tid];
    vvf[256 + tid] = vvec[256 + tid];
  }
  __syncthreads();
  // dec_proj partials: unit=(b,h8), 2 threads per unit (k-halves of 256)
  {
    int unit = tid & 127, ksel = tid >> 7;
    int bb = unit >> 6, h8 = unit & 63;
    const short* wp = wdecT + (size_t)(ksel*256)*HH + h8*8;
    const float* hrow = hbf + bb*HH + ksel*256;
    float a[8] = {0.f,0.f,0.f,0.f,0.f,0.f,0.f,0.f};
    for (int k = 0; k < 256; ++k) {
      bf16x8 w8 = *(const bf16x8*)(wp + (size_t)k*HH);
      float x = hrow[k];
      #pragma unroll
      for (int j = 0; j < 8; ++j) a[j] += x * bf2f(w8[j]);
    }
    float* d = dps + (ksel*2 + bb)*HH + h8*8;
    #pragma unroll
    for (int j = 0; j < 8; ++j) d[j] = a[j];
  }
  __syncthreads();
  {   // combine k-halves into dps[bb][*]
    int bb = tid >> 7, h0 = (tid & 127)*4;
    f32x4 s0 = *(f32x4*)&dps[bb*HH + h0];
    f32x4 s1 = *(f32x4*)&dps[(2 + bb)*HH + h0];
    *(f32x4*)&dps[bb*HH + h0] = s0 + s1;
  }
  __syncthreads();
  // scores: unit=(b,s), 2 lanes per unit (h-halves of 256)
  {
    int u = tid >> 1, khalf = tid & 1;
    int bb = u >> 6, s = u & 63;
    const short* ep = enc_proj + ((size_t)(b0+bb)*SS + s)*HH + khalf*256;
    const float* dpp = dps + bb*HH + khalf*256;
    const float* vp  = vvf + khalf*256;
    float accv = 0.f;
    for (int hc = 0; hc < 32; ++hc) {
      bf16x8 e8 = *(const bf16x8*)(ep + hc*8);
      f32x4 d0 = *(const f32x4*)(dpp + hc*8);
      f32x4 d1 = *(const f32x4*)(dpp + hc*8 + 4);
      f32x4 v0 = *(const f32x4*)(vp + hc*8);
      f32x4 v1 = *(const f32x4*)(vp + hc*8 + 4);
      #pragma unroll
      for (int j = 0; j < 4; ++j) accv += v0[j]*tanh_fast(d0[j] + bf2f(e8[j]));
      #pragma unroll
      for (int j = 0; j < 4; ++j) accv += v1[j]*tanh_fast(d1[j] + bf2f(e8[4+j]));
    }
    accv += __shfl_xor(accv, 1, 64);
    if (khalf == 0) sc[bb*64 + s] = accv;
  }
  __syncthreads();
  if (tid < 128) {   // masked softmax: wave0 -> b0, wave1 -> b1
    int bb = tid >> 6, s = tid & 63;
    int valid = mask[(b0+bb)*SS + s];
    float x = valid ? sc[bb*64 + s] : -INFINITY;
    float mx = x;
    #pragma unroll
    for (int off = 32; off; off >>= 1) mx = fmaxf(mx, __shfl_xor(mx, off, 64));
    float e = valid ? __expf(x - mx) : 0.f;
    float sum = e;
    #pragma unroll
    for (int off = 32; off; off >>= 1) sum += __shfl_xor(sum, off, 64);
    wt[bb*64 + s] = e / sum;
  }
  __syncthreads();
  {   // context
    int bb = tid >> 7, d0 = (tid & 127)*8;
    const short* eob = enc_out + (size_t)(b0+bb)*SS*DENC + d0;
    float ca[8] = {0.f,0.f,0.f,0.f,0.f,0.f,0.f,0.f};
    for (int s = 0; s < SS; ++s) {
      float w = wt[bb*64 + s];
      bf16x8 e8 = *(const bf16x8*)(eob + (size_t)s*DENC);
      #pragma unroll
      for (int j = 0; j < 8; ++j) ca[j] += w * bf2f(e8[j]);
    }
    bf16x8 cb8;
    #pragma unroll
    for (int j = 0; j < 8; ++j) cb8[j] = f2bf(ca[j]);
    int b_ = b0 + bb;
    *(bf16x8*)&xcat0[(size_t)b_*XW0 + EE + d0] = cb8;
    *(bf16x8*)&predcat[(size_t)b_*PW + HH + d0] = cb8;
  }
  #pragma unroll
  for (int bb = 0; bb < 2; ++bb) {
    int b_ = b0 + bb;
    int tok = (t == 0) ? 2 : targets[b_*TT + t - 1];
    short ev = embb[tok*EE + tid];
    xcat0[(size_t)b_*XW0 + tid] = ev;
    predcat[(size_t)b_*PW + HH + DENC + tid] = ev;
  }
}

// enc_proj = enc_out @ W_enc.T (M=32768, N=512, K=1024), bf16 out. BM=64, BN=128.
__global__ __launch_bounds__(256)
void enc_gemm(short* __restrict__ C, const short* __restrict__ A, const short* __restrict__ Bt,
              int K, int ldc)
{
  __shared__ __align__(16) char smem[55296];
  short* As = (short*)smem;                    // 2*64*72*2  = 18432
  short* Bs = (short*)(smem + 18432);          // 2*128*72*2 = 36864
  const int tid = threadIdx.x;
  const int rowBase = blockIdx.y*64, colBase = blockIdx.x*128;
  f32x4 acc[2][4];
  #pragma unroll
  for (int i = 0; i < 2; ++i)
    #pragma unroll
    for (int j = 0; j < 4; ++j) acc[i][j] = {0.f,0.f,0.f,0.f};
  GemmPipe<64,128>::run(As, Bs, A, Bt, K, rowBase, colBase, tid, acc);
  const int lane = tid & 63, wave = tid >> 6, ml = lane & 15, kq = lane >> 4;
  const int wm = (wave >> 1)*32, wn = (wave & 1)*64;
  #pragma unroll
  for (int ii = 0; ii < 2; ++ii)
    #pragma unroll
    for (int jj = 0; jj < 4; ++jj) {
      int n = colBase + wn + jj*16 + ml;
      #pragma unroll
      for (int r2 = 0; r2 < 4; ++r2) {
        int m = rowBase + wm + ii*16 + kq*4 + r2;
        C[(size_t)m*ldc + n] = f2bf(acc[ii][jj][r2]);
      }
    }
}

// interleaved (n = 4*h + gate) bf16 weight concat
__global__ __launch_bounds__(256)
void build_wcat_bf(short* __restrict__ wcat0, short* __restrict__ wcat1,
                   const float* __restrict__ wih0, const float* __restrict__ whh0,
                   const float* __restrict__ wih1, const float* __restrict__ whh1)
{
  int idx = blockIdx.x*256 + threadIdx.x;
  const int N0 = G4H*XW0;
  if (idx < N0) {
    int n = idx / XW0, k = idx % XW0;
    int row = (n & 3)*HH + (n >> 2);
    float v = (k < EE+DENC) ? wih0[(size_t)row*(EE+DENC) + k] : whh0[(size_t)row*HH + (k - (EE+DENC))];
    wcat0[idx] = f2bf(v);
  } else {
    int j = idx - N0;
    int n = j / XW1, k = j % XW1;
    int row = (n & 3)*HH + (n >> 2);
    float v = (k < HH) ? wih1[(size_t)row*HH + k] : whh1[(size_t)row*HH + (k - HH)];
    wcat1[j] = f2bf(v);
  }
}

__global__ __launch_bounds__(256)
void cvt_encout(short* __restrict__ dst, const float* __restrict__ src)
{
  size_t i8 = ((size_t)blockIdx.x*256 + threadIdx.x)*8;
  float4 a = *(const float4*)&src[i8];
  float4 b = *(const float4*)&src[i8+4];
  bf16x8 o;
  o[0]=f2bf(a.x); o[1]=f2bf(a.y); o[2]=f2bf(a.z); o[3]=f2bf(a.w);
  o[4]=f2bf(b.x); o[5]=f2bf(b.y); o[6]=f2bf(b.z); o[7]=f2bf(b.w);
  *(bf16x8*)&dst[i8] = o;
}

__global__ __launch_bounds__(256)
void prep_misc(float* __restrict__ cbuf, short* __restrict__ xcat0a, short* __restrict__ xcat1a,
               short* __restrict__ hb, short* __restrict__ wdecT, short* __restrict__ wenc,
               short* __restrict__ wout, short* __restrict__ embb,
               float* __restrict__ bias0i, float* __restrict__ bias1i,
               const float* __restrict__ c0, const float* __restrict__ h0,
               const float* __restrict__ W_dec, const float* __restrict__ W_enc,
               const float* __restrict__ W_out, const float* __restrict__ emb,
               const float* __restrict__ b_ih0, const float* __restrict__ b_hh0,
               const float* __restrict__ b_ih1, const float* __restrict__ b_hh1)
{
  int idx = blockIdx.x*256 + threadIdx.x;
  if (idx < 524288) { cbuf[idx] = c0[idx]; return; }
  idx -= 524288;
  if (idx < 262144) {
    int b = idx >> 9, h = idx & 511;
    xcat0a[(size_t)b*XW0 + EE + DENC + h] = f2bf(h0[idx]);
    return;
  }
  idx -= 262144;
  if (idx < 262144) {
    int b = idx >> 9, h = idx & 511;
    short v = f2bf(h0[BH + idx]);
    xcat1a[(size_t)b*XW1 + HH + h] = v;
    hb[idx] = v;
    return;
  }
  idx -= 262144;
  if (idx < 262144) {                           // wdecT[k][n] = W_dec[n][k]
    int k = idx >> 9, n = idx & 511;
    wdecT[idx] = f2bf(W_dec[(size_t)n*HH + k]);
    return;
  }
  idx -= 262144;
  if (idx < 524288) { wenc[idx] = f2bf(W_enc[idx]); return; }
  idx -= 524288;
  if (idx < 229376) { wout[idx] = f2bf(W_out[idx]); return; }
  idx -= 229376;
  if (idx < 32768)  { embb[idx] = f2bf(emb[idx]); return; }
  idx -= 32768;
  if (idx < 2048) {
    int row = (idx & 3)*HH + (idx >> 2);
    bias0i[idx] = b_ih0[row] + b_hh0[row];
    return;
  }
  idx -= 2048;
  {
    int row = (idx & 3)*HH + (idx >> 2);
    bias1i[idx] = b_ih1[row] + b_hh1[row];
  }
}

extern "C" void kernel_launch(void* const* d_in, const int* in_sizes, int n_in,
                              void* d_out, int out_size, void* d_ws, size_t ws_size,
                              hipStream_t stream) {
  const float* enc_out = (const float*)d_in[0];
  const float* h0      = (const float*)d_in[1];
  const float* c0      = (const float*)d_in[2];
  const int*   targets = (const int*)d_in[3];
  const int*   mask    = (const int*)d_in[4];
  const float* emb     = (const float*)d_in[5];
  const float* W_enc   = (const float*)d_in[6];
  const float* W_dec   = (const float*)d_in[7];
  const float* v       = (const float*)d_in[8];
  const float* b_ih0   = (const float*)d_in[11];
  const float* b_hh0   = (const float*)d_in[12];
  const float* b_ih1   = (const float*)d_in[15];
  const float* b_hh1   = (const float*)d_in[16];
  const float* b_out   = (const float*)d_in[18];
  float* out = (float*)d_out;

  char* ws = (char*)d_ws;
  size_t o = 0;
  short* enc_out_bf = (short*)(ws + o); o += (size_t)BB*SS*DENC*2;
  short* enc_proj_bf= (short*)(ws + o); o += (size_t)BB*SS*HH*2;
  short* wcat0i     = (short*)(ws + o); o += (size_t)G4H*XW0*2;
  short* wcat1i     = (short*)(ws + o); o += (size_t)G4H*XW1*2;
  short* wdecT      = (short*)(ws + o); o += (size_t)HH*HH*2;
  short* wenc_bf    = (short*)(ws + o); o += (size_t)HH*DENC*2;
  short* wout_bf    = (short*)(ws + o); o += (size_t)VV*PW*2;
  short* emb_bf     = (short*)(ws + o); o += (size_t)VV*EE*2;
  short* xcat0a     = (short*)(ws + o); o += (size_t)BB*XW0*2;
  short* xcat0b     = (short*)(ws + o); o += (size_t)BB*XW0*2;
  short* xcat1a     = (short*)(ws + o); o += (size_t)BB*XW1*2;
  short* xcat1b     = (short*)(ws + o); o += (size_t)BB*XW1*2;
  short* predcata   = (short*)(ws + o); o += (size_t)BB*PW*2;
  short* predcatb   = (short*)(ws + o); o += (size_t)BB*PW*2;
  short* hb         = (short*)(ws + o); o += (size_t)BH*2;
  float* cbuf       = (float*)(ws + o); o += (size_t)2*BH*4;
  float* bias0i     = (float*)(ws + o); o += (size_t)G4H*4;
  float* bias1i     = (float*)(ws + o); o += (size_t)G4H*4;
  (void)ws_size; (void)in_sizes; (void)n_in; (void)out_size;

  cvt_encout<<<16384, 256, 0, stream>>>(enc_out_bf, enc_out);
  build_wcat_bf<<<22528, 256, 0, stream>>>(wcat0i, wcat1i,
      (const float*)d_in[9], (const float*)d_in[10], (const float*)d_in[13], (const float*)d_in[14]);
  prep_misc<<<8208, 256, 0, stream>>>(cbuf, xcat0a, xcat1a, hb, wdecT, wenc_bf, wout_bf, emb_bf,
      bias0i, bias1i, c0, h0, W_dec, W_enc, (const float*)d_in[17], emb,
      b_ih0, b_hh0, b_ih1, b_hh1);
  enc_gemm<<<dim3(HH/128, (BB*SS)/64), 256, 0, stream>>>(
      enc_proj_bf, enc_out_bf, wenc_bf, DENC, HH);

  short* xc0[2] = {xcat0a, xcat0b};
  short* xc1[2] = {xcat1a, xcat1b};
  short* pc[2]  = {predcata, predcatb};
  for (int t = 0; t < TT; ++t) {
    attn_out<<<272, 256, 0, stream>>>(enc_proj_bf, enc_out_bf, v, mask, targets, emb_bf,
        hb, wdecT, xc0[t&1], pc[t&1], pc[(t+1)&1], wout_bf, b_out, out, t);
    gates_fused<<<dim3(G4H/64, BB/64), 256, 0, stream>>>(
        xc0[t&1], wcat0i, bias0i, cbuf, xc1[t&1], xc0[(t+1)&1] + EE + DENC, (short*)nullptr, XW0, 0);
    gates_fused<<<dim3(G4H/64, BB/64), 256, 0, stream>>>(
        xc1[t&1], wcat1i, bias1i, cbuf + BH, xc1[(t+1)&1] + HH, pc[t&1], hb, XW1, 1);
  }
  attn_out<<<272, 256, 0, stream>>>(enc_proj_bf, enc_out_bf, v, mask, targets, emb_bf,
      hb, wdecT, xc0[0], pc[0], pc[1], wout_bf, b_out, out, TT);
}